// Round 1
// baseline (919.843 us; speedup 1.0000x reference)
//
#include <hip/hip_runtime.h>
#include <hip/hip_bf16.h>

#define NE 8
#define NT 16384
#define ND 512
#define NF 2048
#define BT 64
#define FC 128

typedef __attribute__((ext_vector_type(8))) short bf16x8;
typedef __attribute__((ext_vector_type(4))) float f32x4;
typedef unsigned short u16;

__device__ __forceinline__ u16 f2bf(float f) {
  union { float f; unsigned u; } c; c.f = f;
  unsigned u = c.u;
  return (u16)((u + 0x7FFFu + ((u >> 16) & 1u)) >> 16);
}

__device__ __forceinline__ float gelu_tanh(float x) {
  // jax.nn.gelu default (approximate=True): 0.5x(1+tanh(sqrt(2/pi)(x+0.044715x^3)))
  float z = 0.7978845608028654f * (x + 0.044715f * x * x * x);
  float e = __expf(2.0f * z);           // inf-safe: e=inf -> th=1; e=0 -> th=-1
  float th = 1.0f - 2.0f / (e + 1.0f);
  return 0.5f * x * (1.0f + th);
}

// Transpose one [R][C] f32 plane per expert -> [C][R] bf16.
__global__ void transpose_bf16(const float* __restrict__ in, u16* __restrict__ out,
                               int R, int C) {
  __shared__ float tile[32][33];
  int e = blockIdx.z;
  const float* ip = in + (size_t)e * R * C;
  u16* op = out + (size_t)e * R * C;
  int c0 = blockIdx.x * 32, r0 = blockIdx.y * 32;
  int tx = threadIdx.x & 31, ty = threadIdx.x >> 5;  // 256 threads: 32 x 8
  for (int i = 0; i < 32; i += 8)
    tile[ty + i][tx] = ip[(size_t)(r0 + ty + i) * C + (c0 + tx)];
  __syncthreads();
  for (int i = 0; i < 32; i += 8)
    op[(size_t)(c0 + ty + i) * R + (r0 + tx)] = f2bf(tile[tx][ty + i]);
}

// Per-expert compaction of mask[e, :] into token index list. One block per expert.
__global__ void compact_mask(const int* __restrict__ mask, int* __restrict__ idx,
                             int* __restrict__ counts) {
  int e = blockIdx.x;
  __shared__ int wsum[4];
  __shared__ int base;
  if (threadIdx.x == 0) base = 0;
  const int* m = mask + (size_t)e * NT;
  int lane = threadIdx.x & 63, w = threadIdx.x >> 6;
  for (int c0 = 0; c0 < NT; c0 += 256) {
    __syncthreads();  // base update visible; wsum reusable
    int i = c0 + threadIdx.x;
    int mi = (m[i] != 0);
    unsigned long long b = __ballot(mi);
    if (lane == 0) wsum[w] = __popcll(b);
    __syncthreads();
    int off = base;
    for (int ww = 0; ww < w; ww++) off += wsum[ww];
    off += __popcll(b & ((1ull << lane) - 1ull));
    if (mi) idx[(size_t)e * NT + off] = i;
    __syncthreads();
    if (threadIdx.x == 0) base += wsum[0] + wsum[1] + wsum[2] + wsum[3];
  }
  __syncthreads();
  if (threadIdx.x == 0) counts[e] = base;
}

// Fused masked-FFN: block = 64 compacted tokens x full D=512 out, 8 waves (2M x 4N).
__launch_bounds__(512)
__global__ void moe_ffn(const float* __restrict__ x,
                        const u16* __restrict__ W1t,   // [E][NF][ND] bf16 (k=d contiguous)
                        const float* __restrict__ b1,  // [E][NF]
                        const u16* __restrict__ W2t,   // [E][ND][NF] bf16 (k=f contiguous)
                        const float* __restrict__ b2,  // [E][ND]
                        const int* __restrict__ idx, const int* __restrict__ counts,
                        float* __restrict__ out) {
  int e = blockIdx.y;
  int cnt = counts[e];
  int r0 = blockIdx.x * BT;
  if (r0 >= cnt) return;
  int rem = cnt - r0; if (rem > BT) rem = BT;

  __shared__ __align__(16) u16 xs[BT * ND];  // 64 KiB, XOR-swizzled
  __shared__ __align__(16) u16 hs[BT * FC];  // 16 KiB, XOR-swizzled

  int tid = threadIdx.x;
  int lane = tid & 63;
  int w = tid >> 6;
  int wm = w & 1, wn = w >> 1;       // 2 (M) x 4 (N) waves
  int l15 = lane & 15, l4 = lane >> 4;

  // ---- stage x tile (gathered rows) into LDS as bf16, swizzle ((row&7)<<3) elems ----
  {
    int cchunk = lane;        // 0..63 -> col0 = 8*lane (wave covers a full 512-col row)
    int rbase = w;            // wave-uniform row
    for (int rp = 0; rp < BT; rp += 8) {
      int row = rp + rbase;
      int t = (row < rem) ? idx[(size_t)e * NT + r0 + row] : -1;
      int col0 = cchunk * 8;
      int eoff = row * ND + (col0 ^ ((row & 7) << 3));
      bf16x8 v;
      if (t >= 0) {
        const float4* p = (const float4*)(x + (size_t)t * ND + col0);
        float4 v0 = p[0], v1 = p[1];
        v[0] = (short)f2bf(v0.x); v[1] = (short)f2bf(v0.y);
        v[2] = (short)f2bf(v0.z); v[3] = (short)f2bf(v0.w);
        v[4] = (short)f2bf(v1.x); v[5] = (short)f2bf(v1.y);
        v[6] = (short)f2bf(v1.z); v[7] = (short)f2bf(v1.w);
      } else {
        v = (bf16x8)0;
      }
      *(bf16x8*)(&xs[eoff]) = v;
    }
  }
  __syncthreads();

  f32x4 yacc[2][8];
  #pragma unroll
  for (int m = 0; m < 2; m++)
    #pragma unroll
    for (int n = 0; n < 8; n++) yacc[m][n] = (f32x4)(0.0f);

  const size_t w1base = (size_t)e * NF * ND;
  const size_t w2base = (size_t)e * ND * NF;

  for (int fc = 0; fc < NF / FC; fc++) {
    int f0 = fc * FC;
    // ---- GEMM1: h[64x128] = xs @ W1[:, f0:f0+128]; wave: rows 32*wm, cols 32*wn ----
    f32x4 acc1[2][2];
    #pragma unroll
    for (int m = 0; m < 2; m++)
      #pragma unroll
      for (int n = 0; n < 2; n++) acc1[m][n] = (f32x4)(0.0f);
    float b1v[2];
    #pragma unroll
    for (int n = 0; n < 2; n++)
      b1v[n] = b1[e * NF + f0 + 32 * wn + n * 16 + l15];

    int rowA0 = 32 * wm + l15;
    int rowA1 = rowA0 + 16;
    #pragma unroll
    for (int k = 0; k < 16; k++) {
      int kk = k * 32 + l4 * 8;
      bf16x8 a0 = *(const bf16x8*)&xs[rowA0 * ND + (kk ^ ((rowA0 & 7) << 3))];
      bf16x8 a1 = *(const bf16x8*)&xs[rowA1 * ND + (kk ^ ((rowA1 & 7) << 3))];
      bf16x8 bb0 = *(const bf16x8*)&W1t[w1base + (size_t)(f0 + 32 * wn + l15) * ND + kk];
      bf16x8 bb1 = *(const bf16x8*)&W1t[w1base + (size_t)(f0 + 32 * wn + 16 + l15) * ND + kk];
      acc1[0][0] = __builtin_amdgcn_mfma_f32_16x16x32_bf16(a0, bb0, acc1[0][0], 0, 0, 0);
      acc1[0][1] = __builtin_amdgcn_mfma_f32_16x16x32_bf16(a0, bb1, acc1[0][1], 0, 0, 0);
      acc1[1][0] = __builtin_amdgcn_mfma_f32_16x16x32_bf16(a1, bb0, acc1[1][0], 0, 0, 0);
      acc1[1][1] = __builtin_amdgcn_mfma_f32_16x16x32_bf16(a1, bb1, acc1[1][1], 0, 0, 0);
    }

    __syncthreads();  // previous chunk's GEMM2 done reading hs
    // ---- GELU + bf16 -> hs (swizzled) ----
    #pragma unroll
    for (int m = 0; m < 2; m++)
      #pragma unroll
      for (int n = 0; n < 2; n++)
        #pragma unroll
        for (int j = 0; j < 4; j++) {
          int row = 32 * wm + m * 16 + l4 * 4 + j;
          int col = 32 * wn + n * 16 + l15;
          float v = acc1[m][n][j] + b1v[n];
          hs[row * FC + (col ^ ((row & 7) << 3))] = f2bf(gelu_tanh(v));
        }
    __syncthreads();

    // ---- GEMM2: yacc[32 x 128] += hs[rows 32*wm..][0:128] @ W2t[cols 128*wn..] ----
    #pragma unroll
    for (int k2 = 0; k2 < 4; k2++) {
      int kk = k2 * 32 + l4 * 8;
      bf16x8 a0 = *(const bf16x8*)&hs[rowA0 * FC + (kk ^ ((rowA0 & 7) << 3))];
      bf16x8 a1 = *(const bf16x8*)&hs[rowA1 * FC + (kk ^ ((rowA1 & 7) << 3))];
      #pragma unroll
      for (int n = 0; n < 8; n++) {
        bf16x8 bb = *(const bf16x8*)&W2t[w2base + (size_t)(128 * wn + n * 16 + l15) * NF + f0 + kk];
        yacc[0][n] = __builtin_amdgcn_mfma_f32_16x16x32_bf16(a0, bb, yacc[0][n], 0, 0, 0);
        yacc[1][n] = __builtin_amdgcn_mfma_f32_16x16x32_bf16(a1, bb, yacc[1][n], 0, 0, 0);
      }
    }
  }

  // ---- epilogue: scatter masked rows, + b2 ----
  #pragma unroll
  for (int m = 0; m < 2; m++) {
    int rloc = 32 * wm + m * 16 + l4 * 4;
    #pragma unroll
    for (int j = 0; j < 4; j++) {
      int row = rloc + j;
      if (row < rem) {
        int t = idx[(size_t)e * NT + r0 + row];
        float* orow = out + ((size_t)e * NT + t) * ND;
        #pragma unroll
        for (int n = 0; n < 8; n++) {
          int col = 128 * wn + n * 16 + l15;
          orow[col] = yacc[m][n][j] + b2[e * ND + col];
        }
      }
    }
  }
}

extern "C" void kernel_launch(void* const* d_in, const int* in_sizes, int n_in,
                              void* d_out, int out_size, void* d_ws, size_t ws_size,
                              hipStream_t stream) {
  const float* x  = (const float*)d_in[0];
  const float* W1 = (const float*)d_in[1];
  const float* b1 = (const float*)d_in[2];
  const float* W2 = (const float*)d_in[3];
  const float* b2 = (const float*)d_in[4];
  const int* mask = (const int*)d_in[5];

  char* ws = (char*)d_ws;
  int* counts = (int*)ws;                                  // 32 B
  int* idx    = (int*)(ws + 1024);                         // 512 KiB
  u16* W1t    = (u16*)(ws + 1024 + (size_t)NE * NT * 4);   // 16 MiB
  u16* W2t    = W1t + (size_t)NE * NF * ND;                // 16 MiB

  hipMemsetAsync(d_out, 0, (size_t)out_size * sizeof(float), stream);
  transpose_bf16<<<dim3(NF / 32, ND / 32, NE), dim3(256), 0, stream>>>(W1, W1t, ND, NF);
  transpose_bf16<<<dim3(ND / 32, NF / 32, NE), dim3(256), 0, stream>>>(W2, W2t, NF, ND);
  compact_mask<<<dim3(NE), dim3(256), 0, stream>>>(mask, idx, counts);
  moe_ffn<<<dim3(NT / BT, NE), dim3(512), 0, stream>>>(x, W1t, b1, W2t, b2, idx, counts,
                                                       (float*)d_out);
}

// Round 2
// 677.859 us; speedup vs baseline: 1.3570x; 1.3570x over previous
//
#include <hip/hip_runtime.h>
#include <hip/hip_bf16.h>

#define NE 8
#define NT 16384
#define ND 512
#define NF 2048
#define BT 64

typedef __attribute__((ext_vector_type(8))) short bf16x8;
typedef __attribute__((ext_vector_type(4))) float f32x4;
typedef unsigned short u16;

__device__ __forceinline__ u16 f2bf(float f) {
  union { float f; unsigned u; } c; c.f = f;
  unsigned u = c.u;
  return (u16)((u + 0x7FFFu + ((u >> 16) & 1u)) >> 16);
}

__device__ __forceinline__ float gelu_tanh(float x) {
  float z = 0.7978845608028654f * (x + 0.044715f * x * x * x);
  float e = __expf(2.0f * z);
  float th = 1.0f - 2.0f / (e + 1.0f);
  return 0.5f * x * (1.0f + th);
}

__device__ __forceinline__ void gl_lds16(const void* g, void* l) {
  __builtin_amdgcn_global_load_lds(
      (const __attribute__((address_space(1))) unsigned int*)g,
      (__attribute__((address_space(3))) unsigned int*)l, 16, 0, 0);
}

// Transpose one [R][C] f32 plane per expert -> [C][R] bf16.
__global__ void transpose_bf16(const float* __restrict__ in, u16* __restrict__ out,
                               int R, int C) {
  __shared__ float tile[32][33];
  int e = blockIdx.z;
  const float* ip = in + (size_t)e * R * C;
  u16* op = out + (size_t)e * R * C;
  int c0 = blockIdx.x * 32, r0 = blockIdx.y * 32;
  int tx = threadIdx.x & 31, ty = threadIdx.x >> 5;
  for (int i = 0; i < 32; i += 8)
    tile[ty + i][tx] = ip[(size_t)(r0 + ty + i) * C + (c0 + tx)];
  __syncthreads();
  for (int i = 0; i < 32; i += 8)
    op[(size_t)(c0 + ty + i) * R + (r0 + tx)] = f2bf(tile[tx][ty + i]);
}

__global__ void x_to_bf16(const float* __restrict__ x, u16* __restrict__ xbf) {
  int i = blockIdx.x * 256 + threadIdx.x;
  float4 v = ((const float4*)x)[i];
  union { u16 s[4]; unsigned long long ll; } o;
  o.s[0] = f2bf(v.x); o.s[1] = f2bf(v.y); o.s[2] = f2bf(v.z); o.s[3] = f2bf(v.w);
  ((unsigned long long*)xbf)[i] = o.ll;
}

// Per-expert compaction of mask[e, :] into token index list. One block per expert.
__global__ void compact_mask(const int* __restrict__ mask, int* __restrict__ idx,
                             int* __restrict__ counts) {
  int e = blockIdx.x;
  __shared__ int wsum[4];
  __shared__ int base;
  if (threadIdx.x == 0) base = 0;
  const int* m = mask + (size_t)e * NT;
  int lane = threadIdx.x & 63, w = threadIdx.x >> 6;
  for (int c0 = 0; c0 < NT; c0 += 256) {
    __syncthreads();
    int i = c0 + threadIdx.x;
    int mi = (m[i] != 0);
    unsigned long long b = __ballot(mi);
    if (lane == 0) wsum[w] = __popcll(b);
    __syncthreads();
    int off = base;
    for (int ww = 0; ww < w; ww++) off += wsum[ww];
    off += __popcll(b & ((1ull << lane) - 1ull));
    if (mi) idx[(size_t)e * NT + off] = i;
    __syncthreads();
    if (threadIdx.x == 0) base += wsum[0] + wsum[1] + wsum[2] + wsum[3];
  }
  __syncthreads();
  if (threadIdx.x == 0) counts[e] = base;
}

// Fused masked-FFN. Block = 64 compacted tokens, 8 waves, each wave 64x64 tiles.
// f-chunks of 512; K-panels of 32 double-buffered via global_load_lds.
__launch_bounds__(512, 2)
__global__ void moe_ffn(const u16* __restrict__ xbf,
                        const u16* __restrict__ W1t,   // [E][NF][ND] bf16
                        const float* __restrict__ b1,
                        const u16* __restrict__ W2t,   // [E][ND][NF] bf16
                        const float* __restrict__ b2,
                        const int* __restrict__ idx, const int* __restrict__ counts,
                        float* __restrict__ out) {
  int e = blockIdx.y;
  int cnt = counts[e];
  int r0 = blockIdx.x * BT;
  if (r0 >= cnt) return;
  int rem = cnt - r0; if (rem > BT) rem = BT;

  __shared__ __align__(16) u16 hs[BT * 512];     // 64 KiB (chunk h, swizzled rows)
  __shared__ __align__(16) u16 wp[2][512 * 32];  // 64 KiB (weight K-panels, dbuf)
  __shared__ __align__(16) u16 xp[2][BT * 32];   // 8 KiB (x K-panels, dbuf)
  __shared__ int ids_s[BT];

  int tid = threadIdx.x;
  int lane = tid & 63;
  int w = tid >> 6;
  int l15 = lane & 15, l4 = lane >> 4;

  if (tid < BT) ids_s[tid] = (tid < rem) ? idx[(size_t)e * NT + r0 + tid] : 0;
  __syncthreads();

  // staging address precompute (pre-swizzled global sources; LDS writes linear)
  int srow_x = (w & 3) * 16 + (lane >> 2);
  long xsrc_base;
  {
    int tok = ids_s[srow_x];
    int kd = ((lane & 3) * 16) ^ (((srow_x >> 1) & 3) << 4);  // bytes in 64B row
    xsrc_base = (long)tok * ND + (kd >> 1);
  }
  int wrow[4]; int wkd[4];
  #pragma unroll
  for (int j = 0; j < 4; j++) {
    int row = (w * 4 + j) * 16 + (lane >> 2);
    wrow[j] = row;
    wkd[j] = ((((lane & 3) * 16) ^ (((row >> 1) & 3) << 4)) >> 1);
  }

  const size_t w1base = (size_t)e * NF * ND;
  const size_t w2base = (size_t)e * ND * NF;

  f32x4 yacc[4][4];
  #pragma unroll
  for (int g = 0; g < 4; g++)
    #pragma unroll
    for (int h = 0; h < 4; h++) yacc[g][h] = (f32x4)(0.0f);

  for (int c = 0; c < 4; ++c) {
    int f0 = c * 512;

    // ================= GEMM1: h[64x512] = x @ W1[:, f0:f0+512] =================
    f32x4 acc1[4][4];
    #pragma unroll
    for (int g = 0; g < 4; g++)
      #pragma unroll
      for (int h = 0; h < 4; h++) acc1[g][h] = (f32x4)(0.0f);

    // prologue stage kb=0 -> buf0
    #pragma unroll
    for (int j = 0; j < 4; j++)
      gl_lds16(W1t + w1base + (size_t)(f0 + wrow[j]) * ND + wkd[j], &wp[0][(w * 4 + j) * 512]);
    if (w < 4) gl_lds16(xbf + xsrc_base, &xp[0][(w & 3) * 512]);
    asm volatile("s_waitcnt vmcnt(0)" ::: "memory");
    __syncthreads();

    for (int kb = 0; kb < 16; ++kb) {
      int cur = kb & 1;
      if (kb < 15) {
        int kn = (kb + 1) * 32;
        #pragma unroll
        for (int j = 0; j < 4; j++)
          gl_lds16(W1t + w1base + (size_t)(f0 + wrow[j]) * ND + kn + wkd[j],
                   &wp[cur ^ 1][(w * 4 + j) * 512]);
        if (w < 4) gl_lds16(xbf + xsrc_base + kn, &xp[cur ^ 1][(w & 3) * 512]);
      }
      bf16x8 a[4], b[4];
      #pragma unroll
      for (int g = 0; g < 4; g++) {
        int row = 16 * g + l15;
        int byteo = row * 64 + ((l4 * 16) ^ (((row >> 1) & 3) << 4));
        a[g] = *(const bf16x8*)((const char*)xp[cur] + byteo);
      }
      #pragma unroll
      for (int h = 0; h < 4; h++) {
        int row = 64 * w + 16 * h + l15;
        int byteo = row * 64 + ((l4 * 16) ^ (((row >> 1) & 3) << 4));
        b[h] = *(const bf16x8*)((const char*)wp[cur] + byteo);
      }
      #pragma unroll
      for (int g = 0; g < 4; g++)
        #pragma unroll
        for (int h = 0; h < 4; h++)
          acc1[g][h] = __builtin_amdgcn_mfma_f32_16x16x32_bf16(a[g], b[h], acc1[g][h], 0, 0, 0);
      asm volatile("s_waitcnt vmcnt(0)" ::: "memory");
      __syncthreads();
    }

    // ---- GELU + bias -> hs (swizzled (row&7)<<4 within 1KiB rows) ----
    float b1v[4];
    #pragma unroll
    for (int h = 0; h < 4; h++) b1v[h] = b1[e * NF + f0 + 64 * w + 16 * h + l15];
    #pragma unroll
    for (int g = 0; g < 4; g++)
      #pragma unroll
      for (int h = 0; h < 4; h++)
        #pragma unroll
        for (int j = 0; j < 4; j++) {
          int row = 16 * g + l4 * 4 + j;
          int col = 64 * w + 16 * h + l15;
          float v = acc1[g][h][j] + b1v[h];
          int byteo = row * 1024 + ((col * 2) ^ ((row & 7) << 4));
          *(u16*)((char*)hs + byteo) = f2bf(gelu_tanh(v));
        }
    __syncthreads();

    // ================= GEMM2: y[64x512] += h @ W2[f0:f0+512, :] =================
    #pragma unroll
    for (int j = 0; j < 4; j++)
      gl_lds16(W2t + w2base + (size_t)wrow[j] * NF + f0 + wkd[j], &wp[0][(w * 4 + j) * 512]);
    asm volatile("s_waitcnt vmcnt(0)" ::: "memory");
    __syncthreads();

    for (int kb = 0; kb < 16; ++kb) {
      int cur = kb & 1;
      if (kb < 15) {
        int kn = f0 + (kb + 1) * 32;
        #pragma unroll
        for (int j = 0; j < 4; j++)
          gl_lds16(W2t + w2base + (size_t)wrow[j] * NF + kn + wkd[j],
                   &wp[cur ^ 1][(w * 4 + j) * 512]);
      }
      bf16x8 a[4], b[4];
      #pragma unroll
      for (int g = 0; g < 4; g++) {
        int row = 16 * g + l15;
        int byteo = row * 1024 + ((kb * 64 + l4 * 16) ^ ((row & 7) << 4));
        a[g] = *(const bf16x8*)((const char*)hs + byteo);
      }
      #pragma unroll
      for (int h = 0; h < 4; h++) {
        int row = 64 * w + 16 * h + l15;
        int byteo = row * 64 + ((l4 * 16) ^ (((row >> 1) & 3) << 4));
        b[h] = *(const bf16x8*)((const char*)wp[cur] + byteo);
      }
      #pragma unroll
      for (int g = 0; g < 4; g++)
        #pragma unroll
        for (int h = 0; h < 4; h++)
          yacc[g][h] = __builtin_amdgcn_mfma_f32_16x16x32_bf16(a[g], b[h], yacc[g][h], 0, 0, 0);
      asm volatile("s_waitcnt vmcnt(0)" ::: "memory");
      __syncthreads();
    }
  }

  // ---- epilogue: scatter masked rows, + b2 ----
  #pragma unroll
  for (int g = 0; g < 4; g++)
    #pragma unroll
    for (int j = 0; j < 4; j++) {
      int row = 16 * g + l4 * 4 + j;
      if (row < rem) {
        int tok = ids_s[row];
        float* orow = out + ((size_t)e * NT + tok) * ND;
        #pragma unroll
        for (int h = 0; h < 4; h++) {
          int col = 64 * w + 16 * h + l15;
          orow[col] = yacc[g][h][j] + b2[e * ND + col];
        }
      }
    }
}

extern "C" void kernel_launch(void* const* d_in, const int* in_sizes, int n_in,
                              void* d_out, int out_size, void* d_ws, size_t ws_size,
                              hipStream_t stream) {
  const float* x  = (const float*)d_in[0];
  const float* W1 = (const float*)d_in[1];
  const float* b1 = (const float*)d_in[2];
  const float* W2 = (const float*)d_in[3];
  const float* b2 = (const float*)d_in[4];
  const int* mask = (const int*)d_in[5];

  char* ws = (char*)d_ws;
  int* counts = (int*)ws;                                   // 32 B
  int* idx    = (int*)(ws + 1024);                          // 512 KiB
  u16* W1t    = (u16*)(ws + 1024 + (size_t)NE * NT * 4);    // 16 MiB
  u16* W2t    = W1t + (size_t)NE * NF * ND;                 // 16 MiB
  u16* xbf    = W2t + (size_t)NE * ND * NF;                 // 16 MiB

  hipMemsetAsync(d_out, 0, (size_t)out_size * sizeof(float), stream);
  transpose_bf16<<<dim3(NF / 32, ND / 32, NE), dim3(256), 0, stream>>>(W1, W1t, ND, NF);
  transpose_bf16<<<dim3(ND / 32, NF / 32, NE), dim3(256), 0, stream>>>(W2, W2t, NF, ND);
  x_to_bf16<<<dim3(NT * ND / 4 / 256), dim3(256), 0, stream>>>(x, xbf);
  compact_mask<<<dim3(NE), dim3(256), 0, stream>>>(mask, idx, counts);
  moe_ffn<<<dim3(NT / BT, NE), dim3(512), 0, stream>>>(xbf, W1t, b1, W2t, b2, idx, counts,
                                                       (float*)d_out);
}

// Round 3
// 429.682 us; speedup vs baseline: 2.1408x; 1.5776x over previous
//
#include <hip/hip_runtime.h>
#include <hip/hip_bf16.h>

#define NE 8
#define NT 16384
#define ND 512
#define NF 2048
#define BT 64

typedef __attribute__((ext_vector_type(8))) short bf16x8;
typedef __attribute__((ext_vector_type(4))) float f32x4;
typedef unsigned short u16;

#define WAITV(n) asm volatile("s_waitcnt vmcnt(" #n ")" ::: "memory")

__device__ __forceinline__ u16 f2bf(float f) {
  union { float f; unsigned u; } c; c.f = f;
  unsigned u = c.u;
  return (u16)((u + 0x7FFFu + ((u >> 16) & 1u)) >> 16);
}

__device__ __forceinline__ float gelu_tanh(float x) {
  float z = 0.7978845608028654f * (x + 0.044715f * x * x * x);
  float e = __expf(2.0f * z);
  float th = 1.0f - 2.0f * __builtin_amdgcn_rcpf(e + 1.0f);
  return 0.5f * x * (1.0f + th);
}

__device__ __forceinline__ void gl_lds16(const void* g, void* l) {
  __builtin_amdgcn_global_load_lds(
      (const __attribute__((address_space(1))) unsigned int*)g,
      (__attribute__((address_space(3))) unsigned int*)l, 16, 0, 0);
}

// Pack weights into staged-panel images (swizzle pre-applied, byte-exact LDS image).
// MODE 0: W1 [E][512 d][2048 f] -> panels (e, c=f/256, kb=d/32): [256 f][32 d] bf16, 16 KB.
// MODE 1: W2 [E][2048 f][512 d] -> panels (e, c=f/256, kb=(f%256)/32): [512 d][32 f] bf16, 32 KB.
template<int MODE>
__global__ void pack_w(const float* __restrict__ in, u16* __restrict__ outp) {
  constexpr int K = MODE ? 2048 : 512;
  constexpr int R = MODE ? 512 : 2048;
  __shared__ float tile[32][33];
  int e = blockIdx.z, bx = blockIdx.x, by = blockIdx.y;
  int k0 = bx * 32, r0 = by * 32;
  int tx = threadIdx.x & 31, ty = threadIdx.x >> 5;
  const float* ip = in + ((size_t)e * K + k0) * R + r0;
  #pragma unroll
  for (int i = 0; i < 4; i++)
    tile[ty + i * 8][tx] = ip[(size_t)(ty + i * 8) * R + tx];
  __syncthreads();
  size_t base; int rowb;
  if (MODE == 0) { base = (((size_t)e * 8 + (by >> 3)) * 16 + bx) * 8192; rowb = (by & 7) * 32; }
  else           { base = (((size_t)e * 8 + (bx >> 3)) * 8 + (bx & 7)) * 16384; rowb = by * 32; }
  int row = rowb + tx;
  int byo = row * 64 + ((ty * 8) ^ (((row >> 1) & 3) << 4));
  union { u16 s[4]; ushort4 v; } o;
  #pragma unroll
  for (int j = 0; j < 4; j++) o.s[j] = f2bf(tile[ty * 4 + j][tx]);
  *(ushort4*)((char*)outp + base * 2 + byo) = o.v;
}

__global__ void x_to_bf16(const float* __restrict__ x, u16* __restrict__ xbf) {
  int i = blockIdx.x * 256 + threadIdx.x;
  float4 v = ((const float4*)x)[i];
  union { u16 s[4]; unsigned long long ll; } o;
  o.s[0] = f2bf(v.x); o.s[1] = f2bf(v.y); o.s[2] = f2bf(v.z); o.s[3] = f2bf(v.w);
  ((unsigned long long*)xbf)[i] = o.ll;
}

__global__ void compact_mask(const int* __restrict__ mask, int* __restrict__ idx,
                             int* __restrict__ counts) {
  int e = blockIdx.x;
  __shared__ int wsum[4];
  __shared__ int base;
  if (threadIdx.x == 0) base = 0;
  const int* m = mask + (size_t)e * NT;
  int lane = threadIdx.x & 63, w = threadIdx.x >> 6;
  for (int c0 = 0; c0 < NT; c0 += 256) {
    __syncthreads();
    int i = c0 + threadIdx.x;
    int mi = (m[i] != 0);
    unsigned long long b = __ballot(mi);
    if (lane == 0) wsum[w] = __popcll(b);
    __syncthreads();
    int off = base;
    for (int ww = 0; ww < w; ww++) off += wsum[ww];
    off += __popcll(b & ((1ull << lane) - 1ull));
    if (mi) idx[(size_t)e * NT + off] = i;
    __syncthreads();
    if (threadIdx.x == 0) base += wsum[0] + wsum[1] + wsum[2] + wsum[3];
  }
  __syncthreads();
  if (threadIdx.x == 0) counts[e] = base;
}

// Fused masked-FFN. 8 waves, BT=64 tokens/block, f-chunks of 256, K-panels of 32,
// 3-slot rotating arena with counted-vmcnt staging (packed panel images, coalesced).
__launch_bounds__(512, 2)
__global__ void moe_ffn(const u16* __restrict__ xbf, const u16* __restrict__ W1p,
                        const float* __restrict__ b1f, const u16* __restrict__ W2p,
                        const float* __restrict__ b2f,
                        const int* __restrict__ idx, const int* __restrict__ counts,
                        float* __restrict__ out) {
  int e = blockIdx.y;
  int cnt = counts[e];
  int r0 = blockIdx.x * BT;
  if (r0 >= cnt) return;
  int rem = cnt - r0; if (rem > BT) rem = BT;

  __shared__ __align__(16) u16 arena[3 * 16384];   // 3 slots x 32 KB
  __shared__ __align__(16) u16 hs[BT * 256];       // 32 KB
  __shared__ __align__(16) float b1s[NF];          // 8 KB
  __shared__ __align__(16) float b2s[ND];          // 2 KB
  __shared__ int ids_s[BT];

  int tid = threadIdx.x, lane = tid & 63, w = tid >> 6;
  int wm = w & 1, wn = w >> 1;  // waves: 2(M) x 4(N)
  int l15 = lane & 15, l4 = lane >> 4;

  if (tid < BT) ids_s[tid] = idx[(size_t)e * NT + r0 + ((tid < rem) ? tid : 0)];
  __syncthreads();

  // x gather source: wave q stages x rows q*16..q*16+15 (waves 0-3 only)
  int q = w & 3;
  int xrow = q * 16 + (lane >> 2);
  size_t xsrc = (size_t)ids_s[xrow] * (ND * 2) +
                (((lane & 3) * 16) ^ (((xrow >> 1) & 3) << 4));  // bytes
  const char* xbyte = (const char*)xbf;

  // ds-read byte offsets
  int aoff[2], boff1[4], hbase[2], hswz[2], boff2[8];
  #pragma unroll
  for (int g = 0; g < 2; g++) {
    int row = wm * 32 + g * 16 + l15;
    aoff[g] = 16384 + row * 64 + ((l4 * 16) ^ (((row >> 1) & 3) << 4));
    hbase[g] = row * 512; hswz[g] = (row & 7) << 4;
  }
  #pragma unroll
  for (int h = 0; h < 4; h++) {
    int row = wn * 64 + h * 16 + l15;
    boff1[h] = row * 64 + ((l4 * 16) ^ (((row >> 1) & 3) << 4));
  }
  #pragma unroll
  for (int h = 0; h < 8; h++) {
    int row = wn * 128 + h * 16 + l15;
    boff2[h] = row * 64 + ((l4 * 16) ^ (((row >> 1) & 3) << 4));
  }

  const char* w1b = (const char*)W1p + (size_t)e * (8 * 16 * 16384);
  const char* w2b = (const char*)W2p + (size_t)e * (8 * 8 * 32768);

  auto STAGE1 = [&](int c, int kb, int s) {
    const char* pb = w1b + ((size_t)c * 16 + kb) * 16384;
    char* lb = (char*)arena + s * 32768;
    gl_lds16(pb + (w * 2 + 0) * 1024 + lane * 16, lb + (w * 2 + 0) * 1024);
    gl_lds16(pb + (w * 2 + 1) * 1024 + lane * 16, lb + (w * 2 + 1) * 1024);
    if (w < 4) gl_lds16(xbyte + xsrc + kb * 64, lb + 16384 + q * 1024);
  };
  auto STAGE2 = [&](int c, int kb, int s) {
    const char* pb = w2b + ((size_t)c * 8 + kb) * 32768;
    char* lb = (char*)arena + s * 32768;
    #pragma unroll
    for (int j = 0; j < 4; j++)
      gl_lds16(pb + (w * 4 + j) * 1024 + lane * 16, lb + (w * 4 + j) * 1024);
  };

  // prologue: biases + first two GEMM1 panels
  gl_lds16((const char*)(b1f + (size_t)e * NF) + w * 1024, (char*)b1s + w * 1024);
  if (w < 2) gl_lds16((const char*)(b2f + (size_t)e * ND) + w * 1024, (char*)b2s + w * 1024);
  STAGE1(0, 0, 0);
  STAGE1(0, 1, 1);

  f32x4 yacc[2][8];
  #pragma unroll
  for (int g = 0; g < 2; g++)
    #pragma unroll
    for (int h = 0; h < 8; h++) yacc[g][h] = (f32x4)(0.0f);

  for (int c = 0; c < 8; ++c) {
    f32x4 acc1[2][4];
    #pragma unroll
    for (int g = 0; g < 2; g++)
      #pragma unroll
      for (int h = 0; h < 4; h++) acc1[g][h] = (f32x4)(0.0f);

    // ---- GEMM1: h[64x256] = x @ W1[:, c*256 .. +256], 16 K-panels ----
    for (int kb = 0; kb < 16; ++kb) {
      int s = kb % 3;
      if (kb == 15) WAITV(0);
      else if (w < 4) WAITV(3);
      else WAITV(2);
      __builtin_amdgcn_s_barrier();
      if (kb < 14) STAGE1(c, kb + 2, (kb + 2) % 3);
      else if (kb == 15) { STAGE2(c, 0, 1); STAGE2(c, 1, 2); }
      const char* lb = (const char*)arena + s * 32768;
      bf16x8 a[2], b[4];
      #pragma unroll
      for (int g = 0; g < 2; g++) a[g] = *(const bf16x8*)(lb + aoff[g]);
      #pragma unroll
      for (int h = 0; h < 4; h++) b[h] = *(const bf16x8*)(lb + boff1[h]);
      #pragma unroll
      for (int g = 0; g < 2; g++)
        #pragma unroll
        for (int h = 0; h < 4; h++)
          acc1[g][h] = __builtin_amdgcn_mfma_f32_16x16x32_bf16(a[g], b[h], acc1[g][h], 0, 0, 0);
    }

    // ---- GELU + bias -> hs ----
    #pragma unroll
    for (int g = 0; g < 2; g++)
      #pragma unroll
      for (int h = 0; h < 4; h++) {
        int col = wn * 64 + h * 16 + l15;
        float bb = b1s[c * 256 + col];
        #pragma unroll
        for (int j = 0; j < 4; j++) {
          int row = wm * 32 + g * 16 + l4 * 4 + j;
          float v = acc1[g][h][j] + bb;
          int byo = row * 512 + ((col * 2) ^ ((row & 7) << 4));
          *(u16*)((char*)hs + byo) = f2bf(gelu_tanh(v));
        }
      }
    asm volatile("s_waitcnt lgkmcnt(0)" ::: "memory");
    __builtin_amdgcn_s_barrier();

    // ---- GEMM2: y[64x512] += h @ W2[c*256 .. +256, :], 8 K-panels ----
    for (int kb = 0; kb < 8; ++kb) {
      int s = (1 + kb) % 3;
      if (kb == 7) WAITV(0);
      else WAITV(4);
      __builtin_amdgcn_s_barrier();
      if (kb < 6) STAGE2(c, kb + 2, (1 + kb + 2) % 3);
      else if (kb == 7 && c < 7) { STAGE1(c + 1, 0, 0); STAGE1(c + 1, 1, 1); }
      const char* lb = (const char*)arena + s * 32768;
      bf16x8 a[2], b[8];
      #pragma unroll
      for (int g = 0; g < 2; g++)
        a[g] = *(const bf16x8*)((const char*)hs + hbase[g] + ((kb * 64 + l4 * 16) ^ hswz[g]));
      #pragma unroll
      for (int h = 0; h < 8; h++) b[h] = *(const bf16x8*)(lb + boff2[h]);
      #pragma unroll
      for (int g = 0; g < 2; g++)
        #pragma unroll
        for (int h = 0; h < 8; h++)
          yacc[g][h] = __builtin_amdgcn_mfma_f32_16x16x32_bf16(a[g], b[h], yacc[g][h], 0, 0, 0);
    }
  }

  // ---- epilogue: scatter masked rows, + b2 ----
  #pragma unroll
  for (int g = 0; g < 2; g++)
    #pragma unroll
    for (int j = 0; j < 4; j++) {
      int row = wm * 32 + g * 16 + l4 * 4 + j;
      if (row < rem) {
        int tok = ids_s[row];
        float* orow = out + ((size_t)e * NT + tok) * ND;
        #pragma unroll
        for (int h = 0; h < 8; h++) {
          int col = wn * 128 + h * 16 + l15;
          orow[col] = yacc[g][h][j] + b2s[col];
        }
      }
    }
}

extern "C" void kernel_launch(void* const* d_in, const int* in_sizes, int n_in,
                              void* d_out, int out_size, void* d_ws, size_t ws_size,
                              hipStream_t stream) {
  const float* x  = (const float*)d_in[0];
  const float* W1 = (const float*)d_in[1];
  const float* b1 = (const float*)d_in[2];
  const float* W2 = (const float*)d_in[3];
  const float* b2 = (const float*)d_in[4];
  const int* mask = (const int*)d_in[5];

  char* ws = (char*)d_ws;
  int* counts = (int*)ws;                                   // 1 KiB region
  int* idx    = (int*)(ws + 1024);                          // 512 KiB
  u16* W1p    = (u16*)(ws + 1024 + (size_t)NE * NT * 4);    // 16 MiB
  u16* W2p    = W1p + (size_t)NE * NF * ND;                 // 16 MiB
  u16* xbf    = W2p + (size_t)NE * ND * NF;                 // 16 MiB

  hipMemsetAsync(d_out, 0, (size_t)out_size * sizeof(float), stream);
  pack_w<0><<<dim3(16, 64, NE), dim3(256), 0, stream>>>(W1, W1p);
  pack_w<1><<<dim3(64, 16, NE), dim3(256), 0, stream>>>(W2, W2p);
  x_to_bf16<<<dim3(NT * ND / 4 / 256), dim3(256), 0, stream>>>(x, xbf);
  compact_mask<<<dim3(NE), dim3(256), 0, stream>>>(mask, idx, counts);
  moe_ffn<<<dim3(NT / BT, NE), dim3(512), 0, stream>>>(xbf, W1p, b1, W2p, b2, idx, counts,
                                                       (float*)d_out);
}